// Round 5
// baseline (11042.381 us; speedup 1.0000x reference)
//
#include <hip/hip_runtime.h>
#include <hip/hip_bf16.h>

#define B_   64
#define T_   512
#define DIN_ 256
#define H_   512

typedef __attribute__((ext_vector_type(2))) _Float16 h16x2;
typedef __attribute__((ext_vector_type(8))) _Float16 h16x8;
typedef __attribute__((ext_vector_type(2))) __fp16  fp16x2r;  // cvt_pkrtz return type
typedef __attribute__((ext_vector_type(4))) float f32x4;
typedef unsigned short u16;
typedef unsigned long long u64;

__device__ __forceinline__ float sigmf(float xv) {
  return 1.0f / (1.0f + __expf(-xv));
}

// Poll one domain's 128 per-wave flags: lane i checks words 2i,2i+1 via one
// u64 load; ballot across the wave. Read-only (no RMW) -> no MALL atomic-unit
// serialization (R4's 16.7us/step was 128 same-word atomicAdds per step).
__device__ __forceinline__ void waitdom(const unsigned* f, int lane) {
  const u64* p = (const u64*)f + lane;
  int guard = 0;
  for (;;) {
    u64 v = __hip_atomic_load(p, __ATOMIC_RELAXED, __HIP_MEMORY_SCOPE_AGENT);
    if (__all((int)((unsigned)v != 0u && (unsigned)(v >> 32) != 0u))) break;
    if (++guard > (1 << 22)) break;   // safety valve: never hang the harness
    __builtin_amdgcn_s_sleep(1);
  }
}

// 16B ring chunk as two 8B relaxed agent atomic loads (coherent at MALL).
__device__ __forceinline__ h16x8 ldring(const u16* p) {
  union { h16x8 h; u64 q[2]; } u;
  u.q[0] = __hip_atomic_load((u64*)p,       __ATOMIC_RELAXED, __HIP_MEMORY_SCOPE_AGENT);
  u.q[1] = __hip_atomic_load((u64*)(p + 4), __ATOMIC_RELAXED, __HIP_MEMORY_SCOPE_AGENT);
  return u.h;
}

__device__ __forceinline__ h16x8 pk8(f32x4 a, f32x4 b) {
  union { h16x8 h; fp16x2r p[4]; } u;   // __fp16 member matches cvt_pkrtz return
  u.p[0] = __builtin_amdgcn_cvt_pkrtz(a.x, a.y);
  u.p[1] = __builtin_amdgcn_cvt_pkrtz(a.z, a.w);
  u.p[2] = __builtin_amdgcn_cvt_pkrtz(b.x, b.y);
  u.p[3] = __builtin_amdgcn_cvt_pkrtz(b.z, b.w);
  return u.h;
}

// Persistent per-WG LSTM slice; fp32 global data, fp16 MFMA compute, fp32 c.
// Sync (R5): per-WAVE flag words flags[domain][t][128]; producer wave does
// s_waitcnt(0) (ring stores acked at MALL) then ONE relaxed store of 1 to its
// own dword. Consumers ballot-poll the 128 words with one u64/lane load.
// No RMW anywhere, no per-step barrier; waves free-run (skew bounded by the
// flag chain; ring depths 8/4 cover reuse distance).
template <int LAYER>
__device__ __forceinline__ void lstm_body(
    const float* __restrict__ xin,
    const float* __restrict__ Wih, const float* __restrict__ Whh,
    const float* __restrict__ bih, const float* __restrict__ bhh,
    float* __restrict__ out,
    unsigned* __restrict__ flags,
    u16* __restrict__ h0ring, u16* __restrict__ h1ring,
    _Float16* wlds, int g, int j0)
{
  constexpr int K    = LAYER ? 1024 : 768;   // Kih + 512 (recurrent)
  constexpr int KP   = K + 8;                // pad keeps rows 16B-aligned, breaks bank stride
  constexpr int KIH  = LAYER ? 512 : 256;
  constexpr int NKB1 = KIH / 32;
  const int tid = threadIdx.x;

  // ---- one-time: stage W slice (64 rows x K) f32 -> fp16 LDS ----
  {
    const int c = tid;                       // float4 chunk within a row
    if (c < (K >> 2)) {
      for (int rho = 0; rho < 64; ++rho) {
        const int gI = rho & 3, jI = (rho >> 2) & 3, nt = rho >> 4;
        const int gr = gI * H_ + j0 + nt * 4 + jI;   // global gate-row
        f32x4 v;
        if (c < (KIH >> 2))
          v = *(const f32x4*)(Wih + (size_t)gr * KIH + (size_t)c * 4);
        else
          v = *(const f32x4*)(Whh + (size_t)gr * H_ + (size_t)(c - (KIH >> 2)) * 4);
        h16x2 q0, q1;                        // scalar casts: RTN rounding for weights
        q0[0] = (_Float16)v.x; q0[1] = (_Float16)v.y;
        q1[0] = (_Float16)v.z; q1[1] = (_Float16)v.w;
        *(h16x2*)(wlds + rho * KP + c * 4)     = q0;
        *(h16x2*)(wlds + rho * KP + c * 4 + 2) = q1;
      }
    }
  }

  const int lane = tid & 63;
  const int w    = tid >> 6;        // wave id == N-tile id
  const int n    = lane & 15;       // output col within 16-wide tile
  const int quad = lane >> 4;
  const int gI   = n & 3;           // gate of this lane's column
  const int jI   = n >> 2;
  const int jglob = j0 + w * 4 + jI;
  const float bias = bih[gI * H_ + jglob] + bhh[gI * H_ + jglob];

  const int mRow0 = g * 32 + n;          // A-operand rows (m = lane&15)
  const int mRow1 = g * 32 + 16 + n;
  const int koffA = quad * 8;            // k offset within 32-wide k-block
  const _Float16* bbase = wlds + (w * 16 + n) * KP + koffA;

  // flag domains: [layer*2+g][T][128 per-wave words]
  unsigned* dom0 = flags + (size_t)(0 * 2 + g) * T_ * 128;
  unsigned* dom1 = flags + (size_t)(1 * 2 + g) * T_ * 128;
  unsigned* myDom = LAYER ? dom1 : dom0;
  const int myWid = (j0 >> 4) * 4 + w;   // this wave's private flag word

  __syncthreads();   // staging done (only barrier in the kernel)

  f32x4 cstate[2] = {{0.f,0.f,0.f,0.f},{0.f,0.f,0.f,0.f}};

  for (int t = 0; t < T_; ++t) {
    f32x4 acc0 = {0.f,0.f,0.f,0.f}, acc1 = {0.f,0.f,0.f,0.f};

    if (LAYER == 0) {
      // ---- part 1: W_ih * x_t — immutable global, no deps: fully overlaps
      // peer skew, runs before any wait.
      const float* a0 = xin + (size_t)mRow0 * (T_ * DIN_) + (size_t)t * DIN_ + koffA;
      const float* a1 = xin + (size_t)mRow1 * (T_ * DIN_) + (size_t)t * DIN_ + koffA;
#pragma unroll
      for (int kb = 0; kb < NKB1; ++kb) {
        h16x8 bf  = *(const h16x8*)(bbase + kb * 32);
        h16x8 af0 = pk8(*(const f32x4*)(a0 + kb * 32), *(const f32x4*)(a0 + kb * 32 + 4));
        h16x8 af1 = pk8(*(const f32x4*)(a1 + kb * 32), *(const f32x4*)(a1 + kb * 32 + 4));
        acc0 = __builtin_amdgcn_mfma_f32_16x16x32_f16(af0, bf, acc0, 0, 0, 0);
        acc1 = __builtin_amdgcn_mfma_f32_16x16x32_f16(af1, bf, acc1, 0, 0, 0);
      }
      // ring backpressure (slot t&7 overwrite; L1 done consuming h0[t-8]).
      // Done before the binding done0[t-1] wait so it overlaps.
      if (t >= 8) waitdom(dom1 + (size_t)(t - 8) * 128, lane);
      // ---- part 2: W_hh * h0[t-1] ----
      if (t > 0) {
        waitdom(dom0 + (size_t)(t - 1) * 128, lane);
        const u16* hb = h0ring + (size_t)((t - 1) & 7) * (B_ * H_);
        const u16* r0 = hb + (size_t)mRow0 * H_ + koffA;
        const u16* r1 = hb + (size_t)mRow1 * H_ + koffA;
        const _Float16* bb2 = bbase + KIH;
#pragma unroll
        for (int kb = 0; kb < 16; ++kb) {
          h16x8 bf  = *(const h16x8*)(bb2 + kb * 32);
          h16x8 af0 = ldring(r0 + kb * 32);
          h16x8 af1 = ldring(r1 + kb * 32);
          acc0 = __builtin_amdgcn_mfma_f32_16x16x32_f16(af0, bf, acc0, 0, 0, 0);
          acc1 = __builtin_amdgcn_mfma_f32_16x16x32_f16(af1, bf, acc1, 0, 0, 0);
        }
      }
    } else {
      // L1 reordered: own-domain W_hh*h1[t-1] FIRST (available early), the
      // cross-layer-dependent W_ih*h0[t] LAST -> after done0[t] is observed
      // only part1 + elementwise remain on the L0->L1 chain.
      if (t > 0) {
        waitdom(dom1 + (size_t)(t - 1) * 128, lane);
        const u16* hb = h1ring + (size_t)((t - 1) & 3) * (B_ * H_);
        const u16* r0 = hb + (size_t)mRow0 * H_ + koffA;
        const u16* r1 = hb + (size_t)mRow1 * H_ + koffA;
        const _Float16* bb2 = bbase + KIH;
#pragma unroll
        for (int kb = 0; kb < 16; ++kb) {
          h16x8 bf  = *(const h16x8*)(bb2 + kb * 32);
          h16x8 af0 = ldring(r0 + kb * 32);
          h16x8 af1 = ldring(r1 + kb * 32);
          acc0 = __builtin_amdgcn_mfma_f32_16x16x32_f16(af0, bf, acc0, 0, 0, 0);
          acc1 = __builtin_amdgcn_mfma_f32_16x16x32_f16(af1, bf, acc1, 0, 0, 0);
        }
      }
      waitdom(dom0 + (size_t)t * 128, lane);
      const u16* hb = h0ring + (size_t)(t & 7) * (B_ * H_);
      const u16* a0 = hb + (size_t)mRow0 * H_ + koffA;
      const u16* a1 = hb + (size_t)mRow1 * H_ + koffA;
#pragma unroll
      for (int kb = 0; kb < NKB1; ++kb) {
        h16x8 bf  = *(const h16x8*)(bbase + kb * 32);
        h16x8 af0 = ldring(a0 + kb * 32);
        h16x8 af1 = ldring(a1 + kb * 32);
        acc0 = __builtin_amdgcn_mfma_f32_16x16x32_f16(af0, bf, acc0, 0, 0, 0);
        acc1 = __builtin_amdgcn_mfma_f32_16x16x32_f16(af1, bf, acc1, 0, 0, 0);
      }
    }

    // ---- elementwise gate math + h/c update (fp32) ----
    u16* ringW = LAYER ? (h1ring + (size_t)(t & 3) * (B_ * H_))
                       : (h0ring + (size_t)(t & 7) * (B_ * H_));
    const bool lastT = (t == T_ - 1);
#pragma unroll
    for (int mt = 0; mt < 2; ++mt) {
      f32x4& acc = mt ? acc1 : acc0;
#pragma unroll
      for (int r = 0; r < 4; ++r) {
        float pre = acc[r] + bias;
        float vi = __shfl(pre, 0, 4);   // quad lanes hold i,f,g,o of one unit
        float vf = __shfl(pre, 1, 4);
        float vg = __shfl(pre, 2, 4);
        float vo = __shfl(pre, 3, 4);
        float cnv = sigmf(vf) * cstate[mt][r] + sigmf(vi) * tanhf(vg);
        cstate[mt][r] = cnv;
        float hv = sigmf(vo) * tanhf(cnv);
        float hv2 = __shfl(hv, lane + 4);   // partner column (n+4); used by n in {0,8}
        if ((lane & 7) == 0) {              // n==0 / n==8: pack 2 adjacent cols -> u32
          const int m = g * 32 + mt * 16 + quad * 4 + r;   // C/D row mapping
          _Float16 ha = (_Float16)hv;       // RTN (keep established numerics)
          _Float16 hb2 = (_Float16)hv2;
          union { struct { u16 a, b; } s; unsigned u; } pku;
          pku.s.a = *(const u16*)&ha; pku.s.b = *(const u16*)&hb2;
          __hip_atomic_store((unsigned*)&ringW[(size_t)m * H_ + jglob], pku.u,
                             __ATOMIC_RELAXED, __HIP_MEMORY_SCOPE_AGENT);
        }
        if (lastT && (lane & 3) == 0) {
          const int m = g * 32 + mt * 16 + quad * 4 + r;
          out[64 + LAYER * (B_ * H_) + m * H_ + jglob] = hv;                  // hn
          out[64 + 2 * (B_ * H_) + LAYER * (B_ * H_) + m * H_ + jglob] = cnv; // cn
        }
      }
    }

    // ---- per-wave release: drain ring-store acks, then ONE plain store to
    // this wave's private flag word (no RMW, no barrier) ----
    __builtin_amdgcn_s_waitcnt(0);
    if (lane == 0)
      __hip_atomic_store(myDom + (size_t)t * 128 + myWid, 1u,
                         __ATOMIC_RELAXED, __HIP_MEMORY_SCOPE_AGENT);
  }
}

__global__ void __launch_bounds__(256, 1) lstm_kernel(
    const float* x,
    const float* Wih0, const float* Whh0, const float* bih0, const float* bhh0,
    const float* Wih1, const float* Whh1, const float* bih1, const float* bhh1,
    float* out, unsigned* flags, u16* h0ring, u16* h1ring)
{
  extern __shared__ char smem[];
  _Float16* wlds = (_Float16*)smem;
  const int bid = blockIdx.x;
  const int g = (bid >> 1) & 1;
  const int j0 = (bid >> 2) * 16;
  if ((bid & 1) == 0)
    lstm_body<0>(x, Wih0, Whh0, bih0, bhh0, out, flags, h0ring, h1ring, wlds, g, j0);
  else
    lstm_body<1>(x, Wih1, Whh1, bih1, bhh1, out, flags, h0ring, h1ring, wlds, g, j0);
}

__global__ void init_kernel(unsigned* p, int nw) {
  int i = blockIdx.x * blockDim.x + threadIdx.x;
  if (i < nw) p[i] = 0;
}

__global__ void fc_kernel(const u16* __restrict__ h1last,
                          const float* __restrict__ fcw,
                          const float* __restrict__ fcb,
                          float* __restrict__ out) {
  const int tid = threadIdx.x;
  const int b = tid >> 2, q = tid & 3;
  const u16* hr = h1last + b * H_ + q * 128;
  const float* wr = fcw + q * 128;
  float s = 0.f;
  for (int i = 0; i < 128; ++i) {
    _Float16 hh = *(const _Float16*)&hr[i];
    s += (float)hh * wr[i];
  }
  s += __shfl_xor(s, 1, 4);
  s += __shfl_xor(s, 2, 4);
  if (q == 0) out[b] = s + fcb[0];
}

extern "C" void kernel_launch(void* const* d_in, const int* in_sizes, int n_in,
                              void* d_out, int out_size, void* d_ws, size_t ws_size,
                              hipStream_t stream) {
  const float* x    = (const float*)d_in[0];
  const float* Wih0 = (const float*)d_in[1];
  const float* Whh0 = (const float*)d_in[2];
  const float* bih0 = (const float*)d_in[3];
  const float* bhh0 = (const float*)d_in[4];
  const float* Wih1 = (const float*)d_in[5];
  const float* Whh1 = (const float*)d_in[6];
  const float* bih1 = (const float*)d_in[7];
  const float* bhh1 = (const float*)d_in[8];
  const float* fcw  = (const float*)d_in[9];
  const float* fcb  = (const float*)d_in[10];
  float* out = (float*)d_out;

  // workspace layout (ws re-poisoned each call -> init kernel zeroes flags)
  const int FLAGS_WORDS = 4 * T_ * 128;          // [4 domains][512][128] = 1 MB
  unsigned* flags = (unsigned*)d_ws;
  u16* h0ring = (u16*)((char*)d_ws + FLAGS_WORDS * 4 + 1024);  // [8][64][512] fp16
  u16* h1ring = h0ring + 8 * B_ * H_;                          // [4][64][512] fp16

  init_kernel<<<(FLAGS_WORDS + 255) / 256, 256, 0, stream>>>(flags, FLAGS_WORDS);

  const int ldsBytes = 64 * (1024 + 8) * 2;      // 132096 B
  (void)hipFuncSetAttribute((const void*)lstm_kernel,
                            hipFuncAttributeMaxDynamicSharedMemorySize, ldsBytes);
  // 128 WGs: (layer, batch-group, j-slice). All co-resident (1 WG/CU by LDS).
  lstm_kernel<<<128, 256, ldsBytes, stream>>>(x, Wih0, Whh0, bih0, bhh0,
                                              Wih1, Whh1, bih1, bhh1,
                                              out, flags, h0ring, h1ring);
  fc_kernel<<<1, 256, 0, stream>>>(h1ring + (size_t)((T_ - 1) & 3) * (B_ * H_),
                                   fcw, fcb, out);
}

// Round 6
// 3932.811 us; speedup vs baseline: 2.8078x; 2.8078x over previous
//
#include <hip/hip_runtime.h>
#include <hip/hip_bf16.h>

#define B_   64
#define T_   512
#define DIN_ 256
#define H_   512

typedef __attribute__((ext_vector_type(2))) _Float16 h16x2;
typedef __attribute__((ext_vector_type(8))) _Float16 h16x8;
typedef __attribute__((ext_vector_type(2))) __fp16  fp16x2r;  // cvt_pkrtz return type
typedef __attribute__((ext_vector_type(4))) float f32x4;
typedef unsigned short u16;
typedef unsigned long long u64;

__device__ __forceinline__ float sigmf(float xv) {
  return 1.0f / (1.0f + __expf(-xv));
}

// ---- intra-XCD (L2-coherent) primitives: sc0 = bypass L1, served by the
// XCD-local L2 (~200cyc). Correct ONLY because a domain's 32 WGs share one
// XCD (R6 placement-by-claim). ----
__device__ __forceinline__ unsigned ld_flag_l2(const unsigned* p) {
  unsigned v;
  asm volatile("global_load_dword %0, %1, off sc0\n\ts_waitcnt vmcnt(0)"
               : "=v"(v) : "v"(p) : "memory");
  return v;
}
__device__ __forceinline__ void st_flag_l2(unsigned* p, unsigned v) {
  asm volatile("global_store_dword %0, %1, off sc0" :: "v"(p), "v"(v) : "memory");
}
#define LD16SC0(dst, p) \
  asm volatile("global_load_dwordx4 %0, %1, off sc0" : "=v"(dst) : "v"(p))
__device__ __forceinline__ void waitall16(h16x8* f) {
  asm volatile("s_waitcnt vmcnt(0)"
    : "+v"(f[0]), "+v"(f[1]), "+v"(f[2]),  "+v"(f[3]),
      "+v"(f[4]), "+v"(f[5]), "+v"(f[6]),  "+v"(f[7]),
      "+v"(f[8]), "+v"(f[9]), "+v"(f[10]), "+v"(f[11]),
      "+v"(f[12]),"+v"(f[13]),"+v"(f[14]), "+v"(f[15]) :: "memory");
}

// Poll 32 per-WG flags (one domain-step): lanes 0..31, distinct words, L2-hit.
__device__ __forceinline__ void waitL2(const unsigned* f, int lane) {
  int guard = 0;
  for (;;) {
    unsigned v = (lane < 32) ? ld_flag_l2(f + lane) : 1u;
    if (__all(v != 0u)) break;
    if (++guard > (1 << 20)) break;   // safety valve
  }
}
// Cross-XCD poll (agent scope, MALL) — only on the slack-buffered edges.
__device__ __forceinline__ void waitXC(const unsigned* f, int lane) {
  int guard = 0;
  for (;;) {
    unsigned v = (lane < 32)
      ? __hip_atomic_load((unsigned*)(f + lane), __ATOMIC_RELAXED, __HIP_MEMORY_SCOPE_AGENT)
      : 1u;
    if (__all(v != 0u)) break;
    if (++guard > (1 << 20)) break;
    __builtin_amdgcn_s_sleep(1);
  }
}
// Cross-XCD 16B ring read (agent, MALL-coherent; proven R4/R5 path).
__device__ __forceinline__ h16x8 ldring(const u16* p) {
  union { h16x8 h; u64 q[2]; } u;
  u.q[0] = __hip_atomic_load((u64*)p,       __ATOMIC_RELAXED, __HIP_MEMORY_SCOPE_AGENT);
  u.q[1] = __hip_atomic_load((u64*)(p + 4), __ATOMIC_RELAXED, __HIP_MEMORY_SCOPE_AGENT);
  return u.h;
}

__device__ __forceinline__ h16x8 pk8(f32x4 a, f32x4 b) {
  union { h16x8 h; fp16x2r p[4]; } u;
  u.p[0] = __builtin_amdgcn_cvt_pkrtz(a.x, a.y);
  u.p[1] = __builtin_amdgcn_cvt_pkrtz(a.z, a.w);
  u.p[2] = __builtin_amdgcn_cvt_pkrtz(b.x, b.y);
  u.p[3] = __builtin_amdgcn_cvt_pkrtz(b.z, b.w);
  return u.h;
}

// R6: domain (LAYER, g batch-group-of-16) = 32 WGs on ONE XCD (claimed via
// XCC_ID). Intra-domain recurrence: plain stores (L1 write-through -> L2) +
// sc0 loads + per-WG sc0 flags — all XCD-L2-local. Cross-layer edge (h0->L1)
// and its backpressure: agent atomics through MALL, depth-8 ring, flag
// publication deferred 1 step so MALL ack never gates the recurrence.
// W: staged f32->fp16 in LDS once, then preloaded into VGPR B-frags (no
// per-step LDS traffic). M=16 per domain; one MFMA m-tile.
template <int LAYER>
__device__ __forceinline__ void lstm_body(
    const float* __restrict__ xin,
    const float* __restrict__ Wih, const float* __restrict__ Whh,
    const float* __restrict__ bih, const float* __restrict__ bhh,
    float* __restrict__ out,
    unsigned* __restrict__ iflags, unsigned* __restrict__ cf0,
    unsigned* __restrict__ cf1,
    u16* __restrict__ h0i, u16* __restrict__ h1i, u16* __restrict__ h0x,
    _Float16* wlds, int g, int j0, int slotW)
{
  constexpr int K    = LAYER ? 1024 : 768;
  constexpr int KP   = K + 8;
  constexpr int KIH  = LAYER ? 512 : 256;
  constexpr int NKB1 = KIH / 32;
  const int tid = threadIdx.x;

  // ---- one-time: stage W slice (64 gate-rows x K) f32 -> fp16 LDS ----
  {
    const int c = tid;
    if (c < (K >> 2)) {
      for (int rho = 0; rho < 64; ++rho) {
        const int gI = rho & 3, jI = (rho >> 2) & 3, nt = rho >> 4;
        const int gr = gI * H_ + j0 + nt * 4 + jI;
        f32x4 v;
        if (c < (KIH >> 2))
          v = *(const f32x4*)(Wih + (size_t)gr * KIH + (size_t)c * 4);
        else
          v = *(const f32x4*)(Whh + (size_t)gr * H_ + (size_t)(c - (KIH >> 2)) * 4);
        h16x2 q0, q1;
        q0[0] = (_Float16)v.x; q0[1] = (_Float16)v.y;
        q1[0] = (_Float16)v.z; q1[1] = (_Float16)v.w;
        *(h16x2*)(wlds + rho * KP + c * 4)     = q0;
        *(h16x2*)(wlds + rho * KP + c * 4 + 2) = q1;
      }
    }
  }

  const int lane = tid & 63;
  const int w    = tid >> 6;
  const int n    = lane & 15;
  const int quad = lane >> 4;
  const int gI   = n & 3;
  const int jI   = n >> 2;
  const int jglob = j0 + w * 4 + jI;
  const float bias = bih[gI * H_ + jglob] + bhh[gI * H_ + jglob];
  const int koffA = quad * 8;
  const _Float16* bbase = wlds + (w * 16 + n) * KP + koffA;

  __syncthreads();

  // ---- preload B-frags (weights) from LDS into registers: zero per-step
  // LDS traffic thereafter ----
  h16x8 bA[NKB1], bB[16];
#pragma unroll
  for (int kb = 0; kb < NKB1; ++kb) bA[kb] = *(const h16x8*)(bbase + kb * 32);
#pragma unroll
  for (int kb = 0; kb < 16; ++kb)   bB[kb] = *(const h16x8*)(bbase + KIH + kb * 32);

  unsigned* ifl  = iflags + (size_t)(LAYER * 4 + g) * T_ * 32;  // intra, per-WG
  unsigned* cf0g = cf0 + (size_t)g * T_ * 32;                   // cross L0-done
  unsigned* cf1g = cf1 + (size_t)g * T_ * 32;                   // cross L1-done
  u16* myIr = LAYER ? (h1i + (size_t)g * 4 * 8192) : (h0i + (size_t)g * 8 * 8192);
  u16* h0xg = h0x + (size_t)g * 8 * 8192;

  f32x4 cst = {0.f, 0.f, 0.f, 0.f};

  for (int t = 0; t < T_; ++t) {
    f32x4 acc  = {0.f, 0.f, 0.f, 0.f};
    f32x4 acc2 = {0.f, 0.f, 0.f, 0.f};
    h16x8 ax[16];

    if (LAYER == 0) {
      // part 1: W_ih * x_t — immutable global, no deps, overlaps peer skew
      const float* a0 = xin + (size_t)(g * 16 + n) * (T_ * DIN_) + (size_t)t * DIN_ + koffA;
#pragma unroll
      for (int kb = 0; kb < NKB1; ++kb) {
        h16x8 af = pk8(*(const f32x4*)(a0 + kb * 32), *(const f32x4*)(a0 + kb * 32 + 4));
        acc = __builtin_amdgcn_mfma_f32_16x16x32_f16(af, bA[kb], acc, 0, 0, 0);
      }
      // part 2: W_hh * h0[t-1] — intra-XCD L2 path
      if (t > 0) {
        waitL2(ifl + (size_t)(t - 1) * 32, lane);
        const u16* rb = myIr + (size_t)((t - 1) & 7) * 8192 + n * 512 + koffA;
        h16x8 fr[16];
#pragma unroll
        for (int kb = 0; kb < 16; ++kb) LD16SC0(fr[kb], rb + kb * 32);
        waitall16(fr);
#pragma unroll
        for (int kb = 0; kb < 16; ++kb)
          acc2 = __builtin_amdgcn_mfma_f32_16x16x32_f16(fr[kb], bB[kb], acc2, 0, 0, 0);
      }
      // cross backpressure (slot t&7 reuse); pre-satisfied in steady state
      if (t >= 8) waitXC(cf1g + (size_t)(t - 8) * 32, lane);
    } else {
      // cross wait is pre-satisfied (L0 runs ~8 ahead); issue MALL ring loads
      // first so their latency overlaps the intra poll below
      waitXC(cf0g + (size_t)t * 32, lane);
      const u16* xb = h0xg + (size_t)(t & 7) * 8192 + n * 512 + koffA;
#pragma unroll
      for (int kb = 0; kb < 16; ++kb) ax[kb] = ldring(xb + kb * 32);
      // part 2: W_hh * h1[t-1] — intra-XCD L2 path (the binding chain)
      if (t > 0) {
        waitL2(ifl + (size_t)(t - 1) * 32, lane);
        const u16* rb = myIr + (size_t)((t - 1) & 3) * 8192 + n * 512 + koffA;
        h16x8 fr[16];
#pragma unroll
        for (int kb = 0; kb < 16; ++kb) LD16SC0(fr[kb], rb + kb * 32);
        waitall16(fr);
#pragma unroll
        for (int kb = 0; kb < 16; ++kb)
          acc2 = __builtin_amdgcn_mfma_f32_16x16x32_f16(fr[kb], bB[kb], acc2, 0, 0, 0);
      }
      // part 1: W_ih * h0[t]
#pragma unroll
      for (int kb = 0; kb < 16; ++kb)
        acc = __builtin_amdgcn_mfma_f32_16x16x32_f16(ax[kb], bA[kb], acc, 0, 0, 0);
    }

    // ---- elementwise gate math + h/c update (fp32; tanh via sigmoid) ----
    u16* ringW = myIr + (size_t)(t & (LAYER ? 3 : 7)) * 8192;
    const bool lastT = (t == T_ - 1);
    const bool act = ((lane & 7) == 0);
    unsigned sv[4] = {0, 0, 0, 0};
#pragma unroll
    for (int r = 0; r < 4; ++r) {
      float pre = acc[r] + acc2[r] + bias;
      float vi = __shfl(pre, 0, 4);   // quad lanes hold i,f,g,o of one unit
      float vf = __shfl(pre, 1, 4);
      float vg = __shfl(pre, 2, 4);
      float vo = __shfl(pre, 3, 4);
      float tg  = 2.f * sigmf(2.f * vg) - 1.f;            // tanh(vg)
      float cnv = sigmf(vf) * cst[r] + sigmf(vi) * tg;
      cst[r] = cnv;
      float hv = sigmf(vo) * (2.f * sigmf(2.f * cnv) - 1.f);
      float hv2 = __shfl(hv, lane + 4);                   // partner unit column
      const int m = quad * 4 + r;                         // C/D row = batch row
      if (act) {
        _Float16 ha = (_Float16)hv, hb2 = (_Float16)hv2;  // RTN
        union { struct { u16 a, b; } s; unsigned u; } pku;
        pku.s.a = *(const u16*)&ha; pku.s.b = *(const u16*)&hb2;
        *(unsigned*)&ringW[(size_t)m * 512 + jglob] = pku.u;  // plain: WT L1 -> L2
        sv[r] = pku.u;
      }
      if (lastT && (lane & 3) == 0) {
        const int gb = g * 16 + m;
        out[64 + LAYER * (B_ * H_) + gb * H_ + jglob] = hv;                   // hn
        out[64 + 2 * (B_ * H_) + LAYER * (B_ * H_) + gb * H_ + jglob] = cnv;  // cn
      }
    }

    // ---- publish: drain intra stores (L2 ack ~200cyc; prior-step cross
    // stores long acked), barrier, per-WG flags. Cross flag deferred to t-1
    // so MALL ack is never on the critical path. ----
    asm volatile("s_waitcnt vmcnt(0)" ::: "memory");
    __syncthreads();
    if (tid == 0) {
      st_flag_l2(ifl + (size_t)t * 32 + slotW, 1u);
      if (t > 0)
        __hip_atomic_store((LAYER ? cf1g : cf0g) + (size_t)(t - 1) * 32 + slotW, 1u,
                           __ATOMIC_RELAXED, __HIP_MEMORY_SCOPE_AGENT);
    }
    // cross-ring stores of h0[t] (L0 only), fire-and-forget; drained by the
    // NEXT step's waitcnt, published with cf0[t] one step later
    if (LAYER == 0 && act) {
      u16* xw = h0xg + (size_t)(t & 7) * 8192;
#pragma unroll
      for (int r = 0; r < 4; ++r)
        __hip_atomic_store((unsigned*)&xw[(size_t)(quad * 4 + r) * 512 + jglob], sv[r],
                           __ATOMIC_RELAXED, __HIP_MEMORY_SCOPE_AGENT);
    }
  }

  // final cross flag for t = T-1 (loop publishes only up to T-2)
  asm volatile("s_waitcnt vmcnt(0)" ::: "memory");
  __syncthreads();
  if (LAYER == 0 && tid == 0)
    __hip_atomic_store(cf0g + (size_t)(T_ - 1) * 32 + slotW, 1u,
                       __ATOMIC_RELAXED, __HIP_MEMORY_SCOPE_AGENT);
}

__global__ void __launch_bounds__(256, 1) lstm_kernel(
    const float* x,
    const float* Wih0, const float* Whh0, const float* bih0, const float* bhh0,
    const float* Wih1, const float* Whh1, const float* bih1, const float* bhh1,
    float* out, unsigned* claim, unsigned* iflags, unsigned* cf0, unsigned* cf1,
    u16* h0i, u16* h1i, u16* h0x)
{
  __shared__ unsigned role[2];
  extern __shared__ char smem[];
  _Float16* wlds = (_Float16*)smem;
  if (threadIdx.x == 0) {
    // physical XCD id (HW_REG_XCC_ID = 20); claim a role slot on THIS XCD
    unsigned xcc = __builtin_amdgcn_s_getreg((31 << 11) | 20) & 7u;
    unsigned slot = __hip_atomic_fetch_add(&claim[xcc], 1u,
                                           __ATOMIC_RELAXED, __HIP_MEMORY_SCOPE_AGENT);
    role[0] = xcc; role[1] = slot & 31u;
  }
  __syncthreads();
  const int xcc = role[0], slotW = role[1];
  const int layer = xcc & 1, g = (xcc >> 1) & 3, j0 = slotW * 16;
  if (layer == 0)
    lstm_body<0>(x, Wih0, Whh0, bih0, bhh0, out, iflags, cf0, cf1,
                 h0i, h1i, h0x, wlds, g, j0, slotW);
  else
    lstm_body<1>(x, Wih1, Whh1, bih1, bhh1, out, iflags, cf0, cf1,
                 h0i, h1i, h0x, wlds, g, j0, slotW);
}

__global__ void init_kernel(unsigned* p, int nw) {
  int i = blockIdx.x * blockDim.x + threadIdx.x;
  for (; i < nw; i += gridDim.x * blockDim.x) p[i] = 0;
}

__global__ void fc_kernel(const float* __restrict__ hn1,
                          const float* __restrict__ fcw,
                          const float* __restrict__ fcb,
                          float* __restrict__ out) {
  const int tid = threadIdx.x;
  const int b = tid >> 2, q = tid & 3;
  const float* hr = hn1 + b * H_ + q * 128;
  const float* wr = fcw + q * 128;
  float s = 0.f;
  for (int i = 0; i < 128; ++i) s += hr[i] * wr[i];
  s += __shfl_xor(s, 1, 4);
  s += __shfl_xor(s, 2, 4);
  if (q == 0) out[b] = s + fcb[0];
}

extern "C" void kernel_launch(void* const* d_in, const int* in_sizes, int n_in,
                              void* d_out, int out_size, void* d_ws, size_t ws_size,
                              hipStream_t stream) {
  const float* x    = (const float*)d_in[0];
  const float* Wih0 = (const float*)d_in[1];
  const float* Whh0 = (const float*)d_in[2];
  const float* bih0 = (const float*)d_in[3];
  const float* bhh0 = (const float*)d_in[4];
  const float* Wih1 = (const float*)d_in[5];
  const float* Whh1 = (const float*)d_in[6];
  const float* bih1 = (const float*)d_in[7];
  const float* bhh1 = (const float*)d_in[8];
  const float* fcw  = (const float*)d_in[9];
  const float* fcb  = (const float*)d_in[10];
  float* out = (float*)d_out;

  // ws layout (bytes):
  // claim[256w]@0 | iflags[2*4*512*32w]@1024 | cf0[4*512*32w]@525312 |
  // cf1@787456 | h0i[4][8][8192]u16@1049600 | h1i[4][4][8192]@1573888 |
  // h0x[4][8][8192]@1836032 | end 2360320
  unsigned* claim  = (unsigned*)d_ws;
  unsigned* iflags = (unsigned*)((char*)d_ws + 1024);
  unsigned* cf0    = (unsigned*)((char*)d_ws + 525312);
  unsigned* cf1    = (unsigned*)((char*)d_ws + 787456);
  u16* h0i = (u16*)((char*)d_ws + 1049600);
  u16* h1i = (u16*)((char*)d_ws + 1573888);
  u16* h0x = (u16*)((char*)d_ws + 1836032);

  init_kernel<<<256, 256, 0, stream>>>(claim, 262400);  // claim + all flags

  const int ldsBytes = 64 * (1024 + 8) * 2;  // 132096 B -> forces 1 WG/CU
  (void)hipFuncSetAttribute((const void*)lstm_kernel,
                            hipFuncAttributeMaxDynamicSharedMemorySize, ldsBytes);
  // grid 256 == CU count: with 1 WG/CU, every XCD hosts exactly 32 WGs
  lstm_kernel<<<256, 256, ldsBytes, stream>>>(x, Wih0, Whh0, bih0, bhh0,
                                              Wih1, Whh1, bih1, bhh1,
                                              out, claim, iflags, cf0, cf1,
                                              h0i, h1i, h0x);
  // FC reads layer-1 hn (fp32) already written to out by the LSTM kernel
  fc_kernel<<<1, 256, 0, stream>>>(out + 64 + B_ * H_, fcw, fcb, out);
}